// Round 12
// baseline (93.049 us; speedup 1.0000x reference)
//
#include <hip/hip_runtime.h>

typedef __bf16 bf16;
typedef __bf16 bf16x4 __attribute__((ext_vector_type(4)));
typedef __bf16 bf16x8 __attribute__((ext_vector_type(8)));
typedef float f32x4 __attribute__((ext_vector_type(4)));

#define T_SEQ 2048
#define CDIM  1024
#define QKV_LD 3072
#define MEM   256

// global -> LDS direct DMA, 16B per lane. LDS dest is wave-uniform base + lane*16B.
#define GLOAD_LDS16(gp, lp) __builtin_amdgcn_global_load_lds( \
    (const __attribute__((address_space(1))) unsigned int*)(gp), \
    (__attribute__((address_space(3))) unsigned int*)(lp), 16, 0, 0)

#define BAR() do { __builtin_amdgcn_s_barrier(); asm volatile("" ::: "memory"); } while (0)

// ------------- fused prep: cast x (blocks 0..4095), transpose W_attn (4096..4863),
//               transpose W_proj (4864..5119) -------------
__global__ __launch_bounds__(256) void prep_kernel(const float* __restrict__ x,
                                                   const float* __restrict__ Wa,
                                                   const float* __restrict__ Wp,
                                                   bf16* __restrict__ xb,
                                                   bf16* __restrict__ WaT,
                                                   bf16* __restrict__ WpT) {
    const int bid = blockIdx.x;
    if (bid < 4096) {
        int i = bid * 256 + threadIdx.x;
        float4 v = reinterpret_cast<const float4*>(x)[i];
        bf16x4 o = { (bf16)v.x, (bf16)v.y, (bf16)v.z, (bf16)v.w };
        reinterpret_cast<bf16x4*>(xb)[i] = o;
        return;
    }
    // transpose+cast W[K=1024][N] -> Wt[N][1024]
    const float* W; bf16* Wt; int N, bx, by;
    if (bid < 4864) { W = Wa; Wt = WaT; N = 3072; int idx = bid - 4096; bx = idx % 48; by = idx / 48; }
    else            { W = Wp; Wt = WpT; N = 1024; int idx = bid - 4864; bx = idx % 16; by = idx / 16; }
    __shared__ float tile[64][65];
    const int n0 = bx * 64;
    const int k0 = by * 64;
    const int t  = threadIdx.x;
    const int tr = t >> 4;
    const int tc = (t & 15) * 4;
#pragma unroll
    for (int it = 0; it < 4; ++it) {
        int r = it * 16 + tr;
        float4 v = *reinterpret_cast<const float4*>(&W[(size_t)(k0 + r) * N + n0 + tc]);
        tile[r][tc + 0] = v.x; tile[r][tc + 1] = v.y;
        tile[r][tc + 2] = v.z; tile[r][tc + 3] = v.w;
    }
    __syncthreads();
#pragma unroll
    for (int it = 0; it < 4; ++it) {
        int n = it * 16 + tr;
        bf16x4 o;
#pragma unroll
        for (int j = 0; j < 4; ++j) o[j] = (bf16)tile[tc + j][n];
        *reinterpret_cast<bf16x4*>(&Wt[(size_t)(n0 + n) * 1024 + k0 + tc]) = o;
    }
}

// ------------- 128x192 GEMM, 2 blocks/CU, fine-interleaved, V-transposing epilogue (frozen R11) -------------
__global__ __launch_bounds__(512, 4) void gemm256_kernel(const bf16* __restrict__ A,
                                                         const bf16* __restrict__ Bt,
                                                         bf16* __restrict__ Cb,
                                                         bf16* __restrict__ Vt,
                                                         int M, int N, int K) {
    __shared__ bf16 smA[2][128][64];
    __shared__ bf16 smB[2][192][64];
    const int t    = threadIdx.x;
    const int lane = t & 63;
    const int w    = t >> 6;
    const int wm   = (w >> 2) * 64;      // wave row-half (2 halves of 64)
    const int wn   = (w & 3) * 48;       // wave col-quarter (3 frags of 16)
    const int g    = lane >> 4;
    const int r    = lane & 15;

    const int nwg = gridDim.x, cpx = nwg >> 3;           // 512 % 8 == 0 -> bijective
    const int swz = (blockIdx.x & 7) * cpx + (blockIdx.x >> 3);
    const int ntn = N / 192;
    const int m0 = (swz / ntn) * 128;
    const int n0 = (swz % ntn) * 192;

    const bf16* Ab = A  + (size_t)m0 * K;
    const bf16* Bb = Bt + (size_t)n0 * K;
    const int NT = K >> 6;               // K-tiles of 64

#define STAGE_A(bi, u, kt) do { \
        const bf16* _s = Ab + (size_t)((u) * 64 + w * 8 + (lane >> 3)) * K \
                         + (kt) * 64 + ((lane & 7) ^ (lane >> 3)) * 8; \
        GLOAD_LDS16(_s, &smA[bi][(u) * 64 + w * 8][0]); \
    } while (0)
#define STAGE_B(bi, u, kt) do { \
        const bf16* _s = Bb + (size_t)((u) * 64 + w * 8 + (lane >> 3)) * K \
                         + (kt) * 64 + ((lane & 7) ^ (lane >> 3)) * 8; \
        GLOAD_LDS16(_s, &smB[bi][(u) * 64 + w * 8][0]); \
    } while (0)

    const int ch0 = ((g     ) ^ (r & 7)) * 8;   // read-side swizzle (row&7 == r&7)
    const int ch1 = ((g ^ 4) ^ (r & 7)) * 8;

    const f32x4 zero4 = {0.f, 0.f, 0.f, 0.f};
    f32x4 acc[4][3];
#pragma unroll
    for (int i = 0; i < 4; ++i)
#pragma unroll
        for (int j = 0; j < 3; ++j) acc[i][j] = zero4;

    bf16x8 afr[4][2], bfrA[2][2], bfrB[1][2];

#define MGRP(BF, FNB, NF) do { \
    __builtin_amdgcn_s_setprio(1); \
    _Pragma("unroll") \
    for (int fm2 = 0; fm2 < 4; ++fm2) \
    _Pragma("unroll") \
    for (int fn2 = 0; fn2 < (NF); ++fn2) \
    _Pragma("unroll") \
    for (int kh = 0; kh < 2; ++kh) \
        acc[fm2][(FNB)+fn2] = __builtin_amdgcn_mfma_f32_16x16x32_bf16( \
            afr[fm2][kh], BF[fn2][kh], acc[fm2][(FNB)+fn2], 0, 0, 0); \
    __builtin_amdgcn_s_setprio(0); } while (0)

    // ---- prologue: T0 all 5 units + T1 A-units (2); wait T0 landed ----
    STAGE_A(0, 0, 0); STAGE_A(0, 1, 0);
    STAGE_B(0, 0, 0); STAGE_B(0, 1, 0); STAGE_B(0, 2, 0);
    STAGE_A(1, 0, 1); STAGE_A(1, 1, 1);
    asm volatile("s_waitcnt vmcnt(2)" ::: "memory");
    __builtin_amdgcn_sched_barrier(0);
    BAR();

    for (int kt = 0; kt < NT; ++kt) {
        const int cur = kt & 1, nxt = cur ^ 1;
#pragma unroll
        for (int i = 0; i < 4; ++i) {
            afr[i][0] = *reinterpret_cast<const bf16x8*>(&smA[cur][wm + i * 16 + r][ch0]);
            afr[i][1] = *reinterpret_cast<const bf16x8*>(&smA[cur][wm + i * 16 + r][ch1]);
        }
#pragma unroll
        for (int fn = 0; fn < 2; ++fn) {
            bfrA[fn][0] = *reinterpret_cast<const bf16x8*>(&smB[cur][wn + fn * 16 + r][ch0]);
            bfrA[fn][1] = *reinterpret_cast<const bf16x8*>(&smB[cur][wn + fn * 16 + r][ch1]);
        }
        bfrB[0][0] = *reinterpret_cast<const bf16x8*>(&smB[cur][wn + 32 + r][ch0]);
        bfrB[0][1] = *reinterpret_cast<const bf16x8*>(&smB[cur][wn + 32 + r][ch1]);
        if (kt + 1 < NT) { STAGE_B(nxt, 0, kt + 1); STAGE_B(nxt, 1, kt + 1); STAGE_B(nxt, 2, kt + 1); }
        __builtin_amdgcn_sched_barrier(0);
        BAR();

        MGRP(bfrA, 0, 2);
        if (kt + 2 < NT) STAGE_A(cur, 0, kt + 2);
        MGRP(bfrB, 2, 1);
        if (kt + 2 < NT) STAGE_A(cur, 1, kt + 2);

        if (kt >= NT - 2)      { asm volatile("s_waitcnt vmcnt(0)" ::: "memory"); }
        else                   { asm volatile("s_waitcnt vmcnt(2)" ::: "memory"); }
        __builtin_amdgcn_sched_barrier(0);
        BAR();
    }

    // ---- epilogue: Q/K cols -> qkv rows; V cols (>=2048) -> Vt[b][h][d][t] (bf16x4) ----
#pragma unroll
    for (int fm = 0; fm < 4; ++fm)
#pragma unroll
        for (int fn = 0; fn < 3; ++fn) {
            const int col  = n0 + wn + fn * 16 + r;
            const int row0 = m0 + wm + fm * 16 + g * 4;
            if (col < 2 * CDIM) {
#pragma unroll
                for (int e = 0; e < 4; ++e)
                    Cb[(size_t)(row0 + e) * N + col] = (bf16)acc[fm][fn][e];
            } else {
                const int hd = col - 2 * CDIM;
                const int bb = row0 >> 11, tt = row0 & (T_SEQ - 1);
                bf16x4 v = { (bf16)acc[fm][fn][0], (bf16)acc[fm][fn][1],
                             (bf16)acc[fm][fn][2], (bf16)acc[fm][fn][3] };
                *reinterpret_cast<bf16x4*>(&Vt[((size_t)(bb * 16 + (hd >> 6)) * 64 + (hd & 63)) * T_SEQ + tt]) = v;
            }
        }
#undef STAGE_A
#undef STAGE_B
#undef MGRP
}

// ------------- proj GEMM: 128x64 tiles, 512 blocks = 2/CU (frozen R10) -------------
__global__ __launch_bounds__(256) void proj_kernel(const bf16* __restrict__ A,
                                                   const bf16* __restrict__ Bt,
                                                   float* __restrict__ Cf,
                                                   int M, int N, int K) {
    __shared__ bf16 As[128 * 32];
    __shared__ bf16 Bs[64 * 32];
    const int t    = threadIdx.x;
    const int lane = t & 63;
    const int w    = t >> 6;
    const int wm   = (w >> 1) * 64;
    const int wn   = (w & 1) * 32;
    const int g    = lane >> 4;
    const int r    = lane & 15;
    const int m0   = blockIdx.y * 128;
    const int n0   = blockIdx.x * 64;

    const bf16* Ab = A  + (size_t)m0 * K;
    const bf16* Bb = Bt + (size_t)n0 * K;
    const bf16* Ag0 = Ab + (size_t)(w * 32 + (lane >> 2)) * K + (lane & 3) * 8;
    const bf16* Ag1 = Ab + (size_t)(w * 32 + 16 + (lane >> 2)) * K + (lane & 3) * 8;
    const bf16* Bg0 = Bb + (size_t)(w * 16 + (lane >> 2)) * K + (lane & 3) * 8;

    bf16* ldsA0 = As + (w * 32) * 32;
    bf16* ldsA1 = As + (w * 32 + 16) * 32;
    bf16* ldsB0 = Bs + (w * 16) * 32;

    const f32x4 zero4 = {0.f, 0.f, 0.f, 0.f};
    f32x4 acc[4][2];
#pragma unroll
    for (int i = 0; i < 4; ++i)
#pragma unroll
        for (int j = 0; j < 2; ++j) acc[i][j] = zero4;

    for (int k0 = 0; k0 < K; k0 += 32) {
        __syncthreads();
        GLOAD_LDS16(Ag0 + k0, ldsA0);
        GLOAD_LDS16(Ag1 + k0, ldsA1);
        GLOAD_LDS16(Bg0 + k0, ldsB0);
        __syncthreads();

        bf16x8 af[4], bfr[2];
#pragma unroll
        for (int i = 0; i < 4; ++i)
            af[i]  = *reinterpret_cast<const bf16x8*>(&As[(wm + i * 16 + r) * 32 + g * 8]);
#pragma unroll
        for (int j = 0; j < 2; ++j)
            bfr[j] = *reinterpret_cast<const bf16x8*>(&Bs[(wn + j * 16 + r) * 32 + g * 8]);
#pragma unroll
        for (int i = 0; i < 4; ++i)
#pragma unroll
            for (int j = 0; j < 2; ++j)
                acc[i][j] = __builtin_amdgcn_mfma_f32_16x16x32_bf16(af[i], bfr[j], acc[i][j], 0, 0, 0);
    }

#pragma unroll
    for (int i = 0; i < 4; ++i)
#pragma unroll
        for (int j = 0; j < 2; ++j)
#pragma unroll
            for (int e = 0; e < 4; ++e) {
                int row = m0 + wm + i * 16 + g * 4 + e;
                int col = n0 + wn + j * 16 + r;
                Cf[(size_t)row * N + col] = acc[i][j][e];
            }
}

// ------------- banded flash attention v6: 64-key tiles + interior fast-path + defer-max -------------
// Per iter: 4 x 16-key subtiles (8 QK MFMA, 8 PV MFMA). Interior tiles (j0 in [q0-241, q0-63])
// skip per-element masking. T13: O-rescale only when tile max exceeds m_run + 8 (P <= e^8,
// bf16-safe). V-chunk indices clamped to <=95 (OOB subtiles are mask-path => P=0).
__global__ __launch_bounds__(512) void attn_kernel(const bf16* __restrict__ qkv,
                                                   const bf16* __restrict__ Vt,
                                                   bf16* __restrict__ y) {
    __shared__ bf16 vtl[64 * 384];       // linear; swizzle via source/read XOR
    const int bid  = blockIdx.x;
    const int bh   = bid >> 4;
    const int qblk = bid & 15;
    const int b = bh >> 4, h = bh & 15;
    const int qb0 = qblk * 128;
    const int wlo = qb0 - 256;           // window start (may be negative)
    const int wv   = threadIdx.x >> 6;   // wave 0..7
    const int lane = threadIdx.x & 63;
    const int g = lane >> 4, c = lane & 15;
    const int q0 = qb0 + wv * 16;
    const int q = q0 + c;
    const float NEG_INF = -__builtin_inff();

    const bf16* base = qkv + (size_t)b * T_SEQ * QKV_LD;
    const bf16* Qb = base + h * 64;
    const bf16* Kb = base + CDIM + h * 64;
    const bf16* Vtb = Vt + (size_t)(b * 16 + h) * 64 * T_SEQ;

    // ---- stage V^T window: 48KB linear, 6 gload issues/wave; source pre-swizzled (x = d&14)
#pragma unroll
    for (int i = 0; i < 6; ++i) {
        const int Lb = (wv * 6 + i) * 1024 + lane * 16;
        const int d   = Lb / 768;
        const int c16 = (Lb % 768) >> 4;
        int koff = ((2 * c16) ^ (d & 14)) << 2;
        int gk = wlo + koff;
        gk = gk < 0 ? 0 : gk;
        GLOAD_LDS16(Vtb + (size_t)d * T_SEQ + gk, vtl + (wv * 6 + i) * 512);
    }

    const bf16x8 qf0 = *reinterpret_cast<const bf16x8*>(Qb + (size_t)q * QKV_LD + g * 8);
    const bf16x8 qf1 = *reinterpret_cast<const bf16x8*>(Qb + (size_t)q * QKV_LD + 32 + g * 8);

    __syncthreads();

    const f32x4 zero4 = {0.f, 0.f, 0.f, 0.f};
    f32x4 o[4];
#pragma unroll
    for (int cb = 0; cb < 4; ++cb) o[cb] = zero4;
    float m_run = NEG_INF, l_run = 0.f;

    const int jstart = (q0 - MEM > 0) ? (q0 - MEM) : 0;
    for (int j0 = jstart; j0 < q0 + 16; j0 += 64) {
        // --- load K for 4 subtiles (rows j0+16su+c, clamped) ---
        bf16x8 kf[4][2];
#pragma unroll
        for (int su = 0; su < 4; ++su) {
            int kr = j0 + 16 * su + c; kr = kr < T_SEQ ? kr : T_SEQ - 1;
            kf[su][0] = *reinterpret_cast<const bf16x8*>(Kb + (size_t)kr * QKV_LD + g * 8);
            kf[su][1] = *reinterpret_cast<const bf16x8*>(Kb + (size_t)kr * QKV_LD + 32 + g * 8);
        }
        // --- S^T = mfma(K, Q): 4 independent chains of 2 ---
        f32x4 s[4];
#pragma unroll
        for (int su = 0; su < 4; ++su) {
            s[su] = __builtin_amdgcn_mfma_f32_16x16x32_bf16(kf[su][0], qf0, zero4, 0, 0, 0);
            s[su] = __builtin_amdgcn_mfma_f32_16x16x32_bf16(kf[su][1], qf1, s[su], 0, 0, 0);
        }

        // --- scale + (mask if boundary tile); lane value (su,e) = S[key=j0+16su+4g+e][q=c] ---
        float mt = NEG_INF;
        const bool interior = (j0 + 63 <= q0) && (j0 >= q0 - 241);
        if (interior) {
#pragma unroll
            for (int su = 0; su < 4; ++su)
#pragma unroll
                for (int e = 0; e < 4; ++e) {
                    s[su][e] *= 0.125f;
                    mt = fmaxf(mt, s[su][e]);
                }
        } else {
#pragma unroll
            for (int su = 0; su < 4; ++su)
#pragma unroll
                for (int e = 0; e < 4; ++e) {
                    int ki = j0 + 16 * su + 4 * g + e;
                    float v = (ki <= q && ki >= q - MEM) ? s[su][e] * 0.125f : NEG_INF;
                    s[su][e] = v;
                    mt = fmaxf(mt, v);
                }
        }
        mt = fmaxf(mt, __shfl_xor(mt, 16, 64));
        mt = fmaxf(mt, __shfl_xor(mt, 32, 64));

        // --- T13 defer-max: rescale only when the tile max grew past m_run + 8 ---
        if (!__all(mt <= m_run + 8.f)) {
            const float mnew = fmaxf(m_run, mt);
            const float corr = __expf(m_run - mnew);   // lane-local (q = c)
#pragma unroll
            for (int cb = 0; cb < 4; ++cb) {
                o[cb][0] *= corr; o[cb][1] *= corr; o[cb][2] *= corr; o[cb][3] *= corr;
            }
            l_run *= corr;
            m_run = mnew;
        }

        // --- P = exp(s - m_run), pack to 2 A-fragments; row-sum ---
        float ps = 0.f;
        bf16x8 pav0, pav1;
#pragma unroll
        for (int e = 0; e < 4; ++e) {
            float e0 = __expf(s[0][e] - m_run);
            float e1 = __expf(s[1][e] - m_run);
            float e2 = __expf(s[2][e] - m_run);
            float e3 = __expf(s[3][e] - m_run);
            ps += (e0 + e1) + (e2 + e3);
            pav0[e] = (bf16)e0; pav0[4 + e] = (bf16)e1;
            pav1[e] = (bf16)e2; pav1[4 + e] = (bf16)e3;
        }
        ps += __shfl_xor(ps, 16, 64);
        ps += __shfl_xor(ps, 32, 64);
        l_run += ps;

        // --- PV as O^T: per cb, 2 MFMA (subtile pairs), V-frags via swizzled ds_read_b64 ---
        const int jrel = j0 - wlo;
        const int c8 = (jrel + 4 * g) >> 2;
        const int c8b1 = (c8 + 4  > 95) ? 95 : (c8 + 4);
        const int c8b2 = (c8 + 8  > 95) ? 95 : (c8 + 8);
        const int c8b3 = (c8 + 12 > 95) ? 95 : (c8 + 12);
#pragma unroll
        for (int cb = 0; cb < 4; ++cb) {
            const int d = cb * 16 + c;
            const int xx = d & 14;
            const bf16* vrow = vtl + d * 384;
            bf16x4 v0 = *reinterpret_cast<const bf16x4*>(vrow + ((c8   ^ xx) << 2));
            bf16x4 v1 = *reinterpret_cast<const bf16x4*>(vrow + ((c8b1 ^ xx) << 2));
            bf16x4 v2 = *reinterpret_cast<const bf16x4*>(vrow + ((c8b2 ^ xx) << 2));
            bf16x4 v3 = *reinterpret_cast<const bf16x4*>(vrow + ((c8b3 ^ xx) << 2));
            bf16x8 vf0 = { v0[0], v0[1], v0[2], v0[3], v1[0], v1[1], v1[2], v1[3] };
            bf16x8 vf1 = { v2[0], v2[1], v2[2], v2[3], v3[0], v3[1], v3[2], v3[3] };
            o[cb] = __builtin_amdgcn_mfma_f32_16x16x32_bf16(vf0, pav0, o[cb], 0, 0, 0);
            o[cb] = __builtin_amdgcn_mfma_f32_16x16x32_bf16(vf1, pav1, o[cb], 0, 0, 0);
        }
    }

    // --- epilogue: o[cb][e] = O[q=q0+c][d = cb*16+4g+e]; lane-local divide; bf16x4 stores ---
    const float linv = 1.0f / l_run;
    bf16* yr = y + (size_t)(b * T_SEQ + q) * CDIM + h * 64 + 4 * g;
#pragma unroll
    for (int cb = 0; cb < 4; ++cb) {
        bf16x4 ov = { (bf16)(o[cb][0] * linv), (bf16)(o[cb][1] * linv),
                      (bf16)(o[cb][2] * linv), (bf16)(o[cb][3] * linv) };
        *reinterpret_cast<bf16x4*>(yr + cb * 16) = ov;
    }
}

// ---------------- launch ----------------
extern "C" void kernel_launch(void* const* d_in, const int* in_sizes, int n_in,
                              void* d_out, int out_size, void* d_ws, size_t ws_size,
                              hipStream_t stream) {
    const float* x      = (const float*)d_in[0];
    const float* W_attn = (const float*)d_in[1];
    const float* W_proj = (const float*)d_in[2];
    float* out = (float*)d_out;

    char* ws = (char*)d_ws;
    bf16* xb   = (bf16*)(ws);                  //  4096x1024 bf16 =  8 MiB
    bf16* WaT  = (bf16*)(ws + 8388608);        //  3072x1024 bf16 =  6 MiB
    bf16* WpT  = (bf16*)(ws + 14680064);       //  1024x1024 bf16 =  2 MiB
    bf16* qkv  = (bf16*)(ws + 16777216);       //  4096x3072 bf16 = 24 MiB (V third unused)
    bf16* yatt = (bf16*)(ws + 41943040);       //  4096x1024 bf16 =  8 MiB
    bf16* Vt   = (bf16*)(ws + 50331648);       //  2x16x64x2048 bf16 = 8 MiB

    prep_kernel<<<5120, 256, 0, stream>>>(x, W_attn, W_proj, xb, WaT, WpT);
    gemm256_kernel<<<512, 512, 0, stream>>>(xb, WaT, qkv, Vt, 4096, 3072, 1024);
    attn_kernel<<<512, 512, 0, stream>>>(qkv, Vt, yatt);
    proj_kernel<<<dim3(16, 32), 256, 0, stream>>>(yatt, WpT, out, 4096, 1024, 1024);
}